// Round 1
// baseline (285.068 us; speedup 1.0000x reference)
//
#include <hip/hip_runtime.h>

// Furthest point sampling: B=64, N=262144, NPOINT=10, out (64,10) int32.
// Strategy: recompute min-distance-to-selected-set each step (selected pts
// live in registers), avoiding a persistent 64MB dists array. xyz (192MB)
// fits in the 256MB Infinity Cache, so steps 2..9 should mostly hit L3.

#define NPOINT 10
#define NB     64
#define NPTS   262144
#define G      64           // blocks (chunks) per batch
#define CH     (NPTS / G)   // 4096 points per block
#define TPB    256
#define PPT    4            // points per thread per pass
#define NPASS  (CH / (TPB * PPT))  // 4

// Strict IEEE distance matching numpy/JAX order: ((dx*dx + dy*dy) + dz*dz),
// no FMA contraction.
__device__ __forceinline__ float sqdist(float x, float y, float z,
                                        float cx, float cy, float cz) {
    float dx = x - cx, dy = y - cy, dz = z - cz;
    return __fadd_rn(__fadd_rn(__fmul_rn(dx, dx), __fmul_rn(dy, dy)),
                     __fmul_rn(dz, dz));
}

// One FPS step. On entry (S>=2): pval_in/pidx_in hold per-chunk argmax
// partials from step S-1. Prologue reduces them -> selected index S-1,
// writes out[b][S-1] and ws_sel[b][S-1]. Main loop computes
// min_{k<S} d(p, sel_k) for every point and the per-chunk argmax ->
// pval_out/pidx_out. Double-buffered partials (in != out) avoid the
// intra-kernel read/overwrite race.
template <int S>
__global__ __launch_bounds__(TPB) void fps_step(
    const float* __restrict__ xyz, int* __restrict__ out,
    float4* __restrict__ ws_sel,
    const float* __restrict__ pval_in, const int* __restrict__ pidx_in,
    float* __restrict__ pval_out, int* __restrict__ pidx_out)
{
    const int b   = blockIdx.y;
    const int g   = blockIdx.x;
    const int tid = threadIdx.x;
    const float* xyzb = xyz + (size_t)b * NPTS * 3;

    __shared__ int   s_newidx;
    __shared__ float s_v[TPB];
    __shared__ int   s_i[TPB];

    // ---- Prologue: assemble selected set sel[0..S-1] in registers ----
    float sx[S], sy[S], sz[S];
    #pragma unroll
    for (int k = 0; k < S - 1; ++k) {        // previously persisted picks
        float4 q = ws_sel[b * NPOINT + k];
        sx[k] = q.x; sy[k] = q.y; sz[k] = q.z;
    }

    int newidx;
    if constexpr (S == 1) {
        newidx = 0;                           // kernel semantics: start at 0
    } else {
        if (tid < 64) {                       // reduce 64 partials, 1 wave
            float v = pval_in[b * G + tid];
            int   i = pidx_in[b * G + tid];
            #pragma unroll
            for (int off = 32; off > 0; off >>= 1) {
                float ov = __shfl_down(v, off);
                int   oi = __shfl_down(i, off);
                if (ov > v || (ov == v && oi < i)) { v = ov; i = oi; }
            }
            if (tid == 0) s_newidx = i;
        }
        __syncthreads();
        newidx = s_newidx;
    }

    float nx = xyzb[(size_t)newidx * 3 + 0];
    float ny = xyzb[(size_t)newidx * 3 + 1];
    float nz = xyzb[(size_t)newidx * 3 + 2];
    sx[S - 1] = nx; sy[S - 1] = ny; sz[S - 1] = nz;
    if (g == 0 && tid == 0) {
        out[b * NPOINT + (S - 1)] = newidx;
        ws_sel[b * NPOINT + (S - 1)] = make_float4(nx, ny, nz, 0.0f);
    }

    // ---- Main: min-dist over selected set, per-chunk argmax ----
    float bestv = -1.0f;
    int   besti = 0;
    const int base = g * CH;
    #pragma unroll
    for (int pass = 0; pass < NPASS; ++pass) {
        const int p0 = base + pass * (TPB * PPT) + tid * PPT;
        const float4* src = (const float4*)(xyzb + (size_t)p0 * 3);
        float4 a = src[0], c = src[1], e = src[2];
        // 4 points from 12 packed floats
        float px[4] = {a.x, a.w, c.z, e.y};
        float py[4] = {a.y, c.x, c.w, e.z};
        float pz[4] = {a.z, c.y, e.x, e.w};
        #pragma unroll
        for (int j = 0; j < PPT; ++j) {
            float dmin = 1e10f;               // INIT_DIST
            #pragma unroll
            for (int k = 0; k < S; ++k)
                dmin = fminf(dmin, sqdist(px[j], py[j], pz[j],
                                          sx[k], sy[k], sz[k]));
            // strictly-greater keeps earliest (ascending p within thread)
            if (dmin > bestv) { bestv = dmin; besti = p0 + j; }
        }
    }

    s_v[tid] = bestv; s_i[tid] = besti;
    __syncthreads();
    #pragma unroll
    for (int stride = TPB / 2; stride > 0; stride >>= 1) {
        if (tid < stride) {
            float ov = s_v[tid + stride]; int oi = s_i[tid + stride];
            if (ov > s_v[tid] || (ov == s_v[tid] && oi < s_i[tid])) {
                s_v[tid] = ov; s_i[tid] = oi;
            }
        }
        __syncthreads();
    }
    if (tid == 0) {
        pval_out[b * G + g] = s_v[0];
        pidx_out[b * G + g] = s_i[0];
    }
}

// Final: reduce step-9 partials -> out[b][9].
__global__ __launch_bounds__(64) void fps_final(
    const float* __restrict__ pval_in, const int* __restrict__ pidx_in,
    int* __restrict__ out)
{
    const int b = blockIdx.x, tid = threadIdx.x;
    float v = pval_in[b * G + tid];
    int   i = pidx_in[b * G + tid];
    #pragma unroll
    for (int off = 32; off > 0; off >>= 1) {
        float ov = __shfl_down(v, off);
        int   oi = __shfl_down(i, off);
        if (ov > v || (ov == v && oi < i)) { v = ov; i = oi; }
    }
    if (tid == 0) out[b * NPOINT + (NPOINT - 1)] = i;
}

extern "C" void kernel_launch(void* const* d_in, const int* in_sizes, int n_in,
                              void* d_out, int out_size, void* d_ws, size_t ws_size,
                              hipStream_t stream) {
    const float* xyz = (const float*)d_in[0];
    int* out = (int*)d_out;

    char* ws = (char*)d_ws;
    float4* ws_sel = (float4*)ws;                      // 64*10*16 = 10240 B
    float*  pval0  = (float*)(ws + 10240);             // 64*64*4 = 16384 B
    float*  pval1  = (float*)(ws + 10240 + 16384);
    int*    pidx0  = (int*)  (ws + 10240 + 32768);
    int*    pidx1  = (int*)  (ws + 10240 + 49152);

    dim3 grid(G, NB), block(TPB);
    // step S: partials in = buf[(S-1)&1], out = buf[S&1]
    fps_step<1><<<grid, block, 0, stream>>>(xyz, out, ws_sel, pval0, pidx0, pval1, pidx1);
    fps_step<2><<<grid, block, 0, stream>>>(xyz, out, ws_sel, pval1, pidx1, pval0, pidx0);
    fps_step<3><<<grid, block, 0, stream>>>(xyz, out, ws_sel, pval0, pidx0, pval1, pidx1);
    fps_step<4><<<grid, block, 0, stream>>>(xyz, out, ws_sel, pval1, pidx1, pval0, pidx0);
    fps_step<5><<<grid, block, 0, stream>>>(xyz, out, ws_sel, pval0, pidx0, pval1, pidx1);
    fps_step<6><<<grid, block, 0, stream>>>(xyz, out, ws_sel, pval1, pidx1, pval0, pidx0);
    fps_step<7><<<grid, block, 0, stream>>>(xyz, out, ws_sel, pval0, pidx0, pval1, pidx1);
    fps_step<8><<<grid, block, 0, stream>>>(xyz, out, ws_sel, pval1, pidx1, pval0, pidx0);
    fps_step<9><<<grid, block, 0, stream>>>(xyz, out, ws_sel, pval0, pidx0, pval1, pidx1);
    fps_final<<<dim3(NB), dim3(64), 0, stream>>>(pval1, pidx1, out);
}